// Round 1
// baseline (463.911 us; speedup 1.0000x reference)
//
#include <hip/hip_runtime.h>

typedef __attribute__((ext_vector_type(4))) int int4v;
typedef __attribute__((ext_vector_type(4))) float float4v;

#define QMAX 127.0f

// ---------------- Per-row absmax int8 quantization ----------------
// One block per row, 256 threads, 16 elements/thread (K must be 4096).
__global__ __launch_bounds__(256) void quant_rows_kernel(
    const float* __restrict__ a, signed char* __restrict__ q,
    float* __restrict__ scale, int K)
{
    const int row = blockIdx.x;
    const int t = threadIdx.x;
    const float* arow = a + (size_t)row * K;

    float4v v[4];
    const float4v* ap = (const float4v*)(arow) + (size_t)t * 4;
#pragma unroll
    for (int i = 0; i < 4; ++i) v[i] = ap[i];

    float m = 0.f;
#pragma unroll
    for (int i = 0; i < 4; ++i) {
        m = fmaxf(m, fabsf(v[i].x));
        m = fmaxf(m, fabsf(v[i].y));
        m = fmaxf(m, fabsf(v[i].z));
        m = fmaxf(m, fabsf(v[i].w));
    }
    // wave (64-lane) reduce, then cross-wave via LDS
#pragma unroll
    for (int off = 32; off > 0; off >>= 1)
        m = fmaxf(m, __shfl_down(m, off, 64));
    __shared__ float wmax[4];
    if ((t & 63) == 0) wmax[t >> 6] = m;
    __syncthreads();
    const float am = fmaxf(fmaxf(wmax[0], wmax[1]), fmaxf(wmax[2], wmax[3]));
    const float s = fmaxf(am, 1e-8f) / QMAX;
    if (t == 0) scale[row] = s;

    int4v packed;
#pragma unroll
    for (int i = 0; i < 4; ++i) {
        // exact fp32 division to match reference rounding decisions; rintf = round-half-even
        int b0 = (int)fminf(fmaxf(rintf(v[i].x / s), -QMAX), QMAX);
        int b1 = (int)fminf(fmaxf(rintf(v[i].y / s), -QMAX), QMAX);
        int b2 = (int)fminf(fmaxf(rintf(v[i].z / s), -QMAX), QMAX);
        int b3 = (int)fminf(fmaxf(rintf(v[i].w / s), -QMAX), QMAX);
        packed[i] = (b0 & 0xff) | ((b1 & 0xff) << 8) | ((b2 & 0xff) << 16) | ((b3 & 0xff) << 24);
    }
    int4v* qp = (int4v*)(q + (size_t)row * K) + t;
    *qp = packed;
}

// ---------------- int8 GEMM, m97 structure ----------------
// C[t,o] = sum_k qx[t,k]*qw[o,k]  (both row-major, K contiguous = B^T form)
// 128x128 tile, BK=64, 256 threads = 4 waves in 2x2, each wave 64x64 via
// 4x4 grid of mfma_i32_16x16x64_i8. global_load_lds width=16.
__global__ __launch_bounds__(256) void gemm_i8_kernel(
    const signed char* __restrict__ qx,   // [M,K]
    const signed char* __restrict__ qw,   // [N,K]
    const float* __restrict__ sx,         // [M]
    const float* __restrict__ sw,         // [N]
    const float* __restrict__ bias,       // [N]
    float* __restrict__ out,              // [M,N]
    int M, int N, int K)
{
    __shared__ signed char smA[128 * 64];
    __shared__ signed char smB[128 * 64];

    const int t = threadIdx.x;
    const int lane = t & 63;
    const int wave = t >> 6;
    const int bm = blockIdx.y, bn = blockIdx.x;
    const int wm = (wave >> 1) * 64;  // wave's row offset in tile
    const int wn = (wave & 1) * 64;   // wave's col offset in tile

    int4v acc[4][4];
#pragma unroll
    for (int i = 0; i < 4; ++i)
#pragma unroll
        for (int j = 0; j < 4; ++j)
            acc[i][j] = (int4v)0;

    // Staging: 128x64 bytes = 512 chunks of 16B; thread t handles chunks t and t+256.
    // chunk ch -> row ch>>2, byte-col (ch&3)*16; LDS dest is contiguous (chunk*16),
    // which matches global_load_lds's wave-uniform-base + lane*16 rule.
    const int r0 = t >> 2;
    const int c0 = (t & 3) * 16;
    const signed char* gA0 = qx + (size_t)(bm * 128 + r0) * K + c0;
    const signed char* gA1 = gA0 + (size_t)64 * K;
    const signed char* gB0 = qw + (size_t)(bn * 128 + r0) * K + c0;
    const signed char* gB1 = gB0 + (size_t)64 * K;
    signed char* lA0 = smA + wave * 1024;         // wave-uniform LDS bases
    signed char* lA1 = smA + 4096 + wave * 1024;
    signed char* lB0 = smB + wave * 1024;
    signed char* lB1 = smB + 4096 + wave * 1024;

    // A-fragment (16x16x64): A[m=lane&15][k=(lane>>4)*16 + j], j=0..15 contiguous bytes
    const int offA = (wm + (lane & 15)) * 64 + (lane >> 4) * 16;
    const int offB = (wn + (lane & 15)) * 64 + (lane >> 4) * 16;

    const int KITER = K >> 6;
    for (int kk = 0; kk < KITER; ++kk) {
        __builtin_amdgcn_global_load_lds((const void*)gA0, (void*)lA0, 16, 0, 0);
        __builtin_amdgcn_global_load_lds((const void*)gA1, (void*)lA1, 16, 0, 0);
        __builtin_amdgcn_global_load_lds((const void*)gB0, (void*)lB0, 16, 0, 0);
        __builtin_amdgcn_global_load_lds((const void*)gB1, (void*)lB1, 16, 0, 0);
        gA0 += 64; gA1 += 64; gB0 += 64; gB1 += 64;
        __syncthreads();

        int4v aF[4], bF[4];
#pragma unroll
        for (int mi = 0; mi < 4; ++mi)
            aF[mi] = *(const int4v*)(smA + offA + mi * 16 * 64);
#pragma unroll
        for (int ni = 0; ni < 4; ++ni)
            bF[ni] = *(const int4v*)(smB + offB + ni * 16 * 64);
#pragma unroll
        for (int mi = 0; mi < 4; ++mi)
#pragma unroll
            for (int ni = 0; ni < 4; ++ni)
                acc[mi][ni] = __builtin_amdgcn_mfma_i32_16x16x64_i8(
                    aF[mi], bF[ni], acc[mi][ni], 0, 0, 0);
        __syncthreads();
    }

    // Epilogue: C/D layout col=lane&15, row=(lane>>4)*4+reg (verified m89/m91)
    const int col0 = lane & 15;
    const int row0 = (lane >> 4) * 4;
#pragma unroll
    for (int mi = 0; mi < 4; ++mi) {
#pragma unroll
        for (int r = 0; r < 4; ++r) {
            const int gm = bm * 128 + wm + mi * 16 + row0 + r;
            const float sxr = sx[gm];
            float* orow = out + (size_t)gm * N + bn * 128 + wn;
#pragma unroll
            for (int ni = 0; ni < 4; ++ni) {
                const int gn_local = ni * 16 + col0;
                const int gn = bn * 128 + wn + gn_local;
                orow[gn_local] = (float)acc[mi][ni][r] * (sxr * sw[gn]) + bias[gn];
            }
        }
    }
    (void)M;
}

extern "C" void kernel_launch(void* const* d_in, const int* in_sizes, int n_in,
                              void* d_out, int out_size, void* d_ws, size_t ws_size,
                              hipStream_t stream) {
    const float* x    = (const float*)d_in[0];
    const float* W    = (const float*)d_in[1];
    const float* bias = (const float*)d_in[2];
    float* out = (float*)d_out;

    const int dout = in_sizes[2];               // 4096
    const int din  = in_sizes[1] / dout;        // 4096
    const int T    = in_sizes[0] / din;         // 8192

    // Workspace layout: qx[T*din] | qw[dout*din] | sx[T] | sw[dout]
    signed char* qx = (signed char*)d_ws;
    signed char* qw = qx + (size_t)T * din;
    float* sx = (float*)(qw + (size_t)dout * din);
    float* sw = sx + T;

    quant_rows_kernel<<<T,    256, 0, stream>>>(x, qx, sx, din);
    quant_rows_kernel<<<dout, 256, 0, stream>>>(W, qw, sw, din);

    dim3 grid(dout / 128, T / 128);
    gemm_i8_kernel<<<grid, 256, 0, stream>>>(qx, qw, sx, sw, bias, out, T, dout, din);

    (void)n_in; (void)out_size; (void)ws_size;
}

// Round 2
// 456.319 us; speedup vs baseline: 1.0166x; 1.0166x over previous
//
#include <hip/hip_runtime.h>

typedef __attribute__((ext_vector_type(4))) int int4v;
typedef __attribute__((ext_vector_type(4))) float float4v;

#define QMAX 127.0f

// ---------------- Per-row absmax int8 quantization ----------------
// One block per row, 256 threads. K must be 4096 (16 elems/thread).
// Lane-contiguous float4 loads: thread t reads float4 indices t + 256*i.
__global__ __launch_bounds__(256) void quant_rows_kernel(
    const float* __restrict__ a, signed char* __restrict__ q,
    float* __restrict__ scale, int K)
{
    const int row = blockIdx.x;
    const int t = threadIdx.x;
    const float4v* ap = (const float4v*)(a + (size_t)row * K);

    float4v v[4];
#pragma unroll
    for (int i = 0; i < 4; ++i) v[i] = ap[t + 256 * i];

    float m = 0.f;
#pragma unroll
    for (int i = 0; i < 4; ++i) {
        m = fmaxf(m, fabsf(v[i].x));
        m = fmaxf(m, fabsf(v[i].y));
        m = fmaxf(m, fabsf(v[i].z));
        m = fmaxf(m, fabsf(v[i].w));
    }
    // wave (64-lane) reduce, then cross-wave via LDS
#pragma unroll
    for (int off = 32; off > 0; off >>= 1)
        m = fmaxf(m, __shfl_down(m, off, 64));
    __shared__ float wmax[4];
    if ((t & 63) == 0) wmax[t >> 6] = m;
    __syncthreads();
    const float am = fmaxf(fmaxf(wmax[0], wmax[1]), fmaxf(wmax[2], wmax[3]));
    const float s = fmaxf(am, 1e-8f) / QMAX;
    if (t == 0) scale[row] = s;

    int* qrow = (int*)(q + (size_t)row * K);
#pragma unroll
    for (int i = 0; i < 4; ++i) {
        // exact fp32 division to match reference rounding decisions; rintf = round-half-even
        int b0 = (int)fminf(fmaxf(rintf(v[i].x / s), -QMAX), QMAX);
        int b1 = (int)fminf(fmaxf(rintf(v[i].y / s), -QMAX), QMAX);
        int b2 = (int)fminf(fmaxf(rintf(v[i].z / s), -QMAX), QMAX);
        int b3 = (int)fminf(fmaxf(rintf(v[i].w / s), -QMAX), QMAX);
        qrow[t + 256 * i] =
            (b0 & 0xff) | ((b1 & 0xff) << 8) | ((b2 & 0xff) << 16) | ((b3 & 0xff) << 24);
    }
}

// ---------------- int8 GEMM, m97 structure + LDS xor-swizzle ----------------
// C[t,o] = sum_k qx[t,k]*qw[o,k]  (both row-major, K contiguous = B^T form)
// 128x128 tile, BK=64, 256 threads = 4 waves in 2x2, each wave 64x64 via
// 4x4 grid of mfma_i32_16x16x64_i8. global_load_lds width=16.
//
// Swizzle: global 16B chunk (row r, col c) is stored at LDS column
// (c + (r>>1)) & 3 (implemented by permuting the *source* address, since
// global_load_lds forces LDS dest = uniform base + lane*16). Readers at
// (row l, K-chunk q) fetch LDS column (q + (l>>1)) & 3 -> any 8 consecutive
// lanes hit 8 distinct bank quads (conflict-free ds_read_b128).
__global__ __launch_bounds__(256) void gemm_i8_kernel(
    const signed char* __restrict__ qx,   // [M,K]
    const signed char* __restrict__ qw,   // [N,K]
    const float* __restrict__ sx,         // [M]
    const float* __restrict__ sw,         // [N]
    const float* __restrict__ bias,       // [N]
    float* __restrict__ out,              // [M,N]
    int M, int N, int K)
{
    __shared__ signed char smA[128 * 64];
    __shared__ signed char smB[128 * 64];

    const int t = threadIdx.x;
    const int lane = t & 63;
    const int wave = t >> 6;
    const int bm = blockIdx.y, bn = blockIdx.x;
    const int wm = (wave >> 1) * 64;  // wave's row offset in tile
    const int wn = (wave & 1) * 64;   // wave's col offset in tile

    int4v acc[4][4];
#pragma unroll
    for (int i = 0; i < 4; ++i)
#pragma unroll
        for (int j = 0; j < 4; ++j)
            acc[i][j] = (int4v)0;

    // Staging: thread t fills LDS chunk position (r = t>>2, c_pos = t&3);
    // the chunk's *content* is global column c_src = (c_pos - (r>>1)) & 3.
    const int r0 = t >> 2;
    const int c_src = ((t & 3) - ((t >> 3) & 3) + 4) & 3;
    const signed char* gA0 = qx + (size_t)(bm * 128 + r0) * K + c_src * 16;
    const signed char* gA1 = gA0 + (size_t)64 * K;
    const signed char* gB0 = qw + (size_t)(bn * 128 + r0) * K + c_src * 16;
    const signed char* gB1 = gB0 + (size_t)64 * K;
    signed char* lA0 = smA + wave * 1024;         // wave-uniform LDS bases
    signed char* lA1 = smA + 4096 + wave * 1024;
    signed char* lB0 = smB + wave * 1024;
    signed char* lB1 = smB + 4096 + wave * 1024;

    // A-fragment (16x16x64): A[m=lane&15][k=(lane>>4)*16 + j], j=0..15.
    // Swizzled LDS column for (row l, chunk q): (q + (l>>1)) & 3.
    const int l16 = lane & 15;
    const int q = lane >> 4;
    const int cr = (q + ((l16 >> 1) & 3)) & 3;
    const int offA = (wm + l16) * 64 + cr * 16;
    const int offB = (wn + l16) * 64 + cr * 16;

    const int KITER = K >> 6;
    for (int kk = 0; kk < KITER; ++kk) {
        __builtin_amdgcn_global_load_lds((const void*)gA0, (void*)lA0, 16, 0, 0);
        __builtin_amdgcn_global_load_lds((const void*)gA1, (void*)lA1, 16, 0, 0);
        __builtin_amdgcn_global_load_lds((const void*)gB0, (void*)lB0, 16, 0, 0);
        __builtin_amdgcn_global_load_lds((const void*)gB1, (void*)lB1, 16, 0, 0);
        gA0 += 64; gA1 += 64; gB0 += 64; gB1 += 64;
        __syncthreads();

        int4v aF[4], bF[4];
#pragma unroll
        for (int mi = 0; mi < 4; ++mi)
            aF[mi] = *(const int4v*)(smA + offA + mi * 16 * 64);
#pragma unroll
        for (int ni = 0; ni < 4; ++ni)
            bF[ni] = *(const int4v*)(smB + offB + ni * 16 * 64);
#pragma unroll
        for (int mi = 0; mi < 4; ++mi)
#pragma unroll
            for (int ni = 0; ni < 4; ++ni)
                acc[mi][ni] = __builtin_amdgcn_mfma_i32_16x16x64_i8(
                    aF[mi], bF[ni], acc[mi][ni], 0, 0, 0);
        __syncthreads();
    }

    // Epilogue: C/D layout col=lane&15, row=(lane>>4)*4+reg (verified m89/m91)
    const int col0 = lane & 15;
    const int row0 = (lane >> 4) * 4;
#pragma unroll
    for (int mi = 0; mi < 4; ++mi) {
#pragma unroll
        for (int r = 0; r < 4; ++r) {
            const int gm = bm * 128 + wm + mi * 16 + row0 + r;
            const float sxr = sx[gm];
            float* orow = out + (size_t)gm * N + bn * 128 + wn;
#pragma unroll
            for (int ni = 0; ni < 4; ++ni) {
                const int gn_local = ni * 16 + col0;
                const int gn = bn * 128 + wn + gn_local;
                orow[gn_local] = (float)acc[mi][ni][r] * (sxr * sw[gn]) + bias[gn];
            }
        }
    }
    (void)M;
}

extern "C" void kernel_launch(void* const* d_in, const int* in_sizes, int n_in,
                              void* d_out, int out_size, void* d_ws, size_t ws_size,
                              hipStream_t stream) {
    const float* x    = (const float*)d_in[0];
    const float* W    = (const float*)d_in[1];
    const float* bias = (const float*)d_in[2];
    float* out = (float*)d_out;

    const int dout = in_sizes[2];               // 4096
    const int din  = in_sizes[1] / dout;        // 4096
    const int T    = in_sizes[0] / din;         // 8192

    // Workspace layout: qx[T*din] | qw[dout*din] | sx[T] | sw[dout]
    signed char* qx = (signed char*)d_ws;
    signed char* qw = qx + (size_t)T * din;
    float* sx = (float*)(qw + (size_t)dout * din);
    float* sw = sx + T;

    quant_rows_kernel<<<T,    256, 0, stream>>>(x, qx, sx, din);
    quant_rows_kernel<<<dout, 256, 0, stream>>>(W, qw, sw, din);

    dim3 grid(dout / 128, T / 128);
    gemm_i8_kernel<<<grid, 256, 0, stream>>>(qx, qw, sx, sw, bias, out, T, dout, din);

    (void)n_in; (void)out_size; (void)ws_size;
}

// Round 3
// 410.300 us; speedup vs baseline: 1.1307x; 1.1122x over previous
//
#include <hip/hip_runtime.h>

typedef __attribute__((ext_vector_type(4))) int int4v;
typedef __attribute__((ext_vector_type(4))) float float4v;

#define QMAX 127.0f

// ---------------- Per-row absmax int8 quantization ----------------
// One block per row, 256 threads. K must be 4096 (16 elems/thread).
__global__ __launch_bounds__(256) void quant_rows_kernel(
    const float* __restrict__ a, signed char* __restrict__ q,
    float* __restrict__ scale, int K)
{
    const int row = blockIdx.x;
    const int t = threadIdx.x;
    const float4v* ap = (const float4v*)(a + (size_t)row * K);

    float4v v[4];
#pragma unroll
    for (int i = 0; i < 4; ++i) v[i] = ap[t + 256 * i];

    float m = 0.f;
#pragma unroll
    for (int i = 0; i < 4; ++i) {
        m = fmaxf(m, fabsf(v[i].x));
        m = fmaxf(m, fabsf(v[i].y));
        m = fmaxf(m, fabsf(v[i].z));
        m = fmaxf(m, fabsf(v[i].w));
    }
#pragma unroll
    for (int off = 32; off > 0; off >>= 1)
        m = fmaxf(m, __shfl_down(m, off, 64));
    __shared__ float wmax[4];
    if ((t & 63) == 0) wmax[t >> 6] = m;
    __syncthreads();
    const float am = fmaxf(fmaxf(wmax[0], wmax[1]), fmaxf(wmax[2], wmax[3]));
    const float s = fmaxf(am, 1e-8f) / QMAX;
    if (t == 0) scale[row] = s;

    int* qrow = (int*)(q + (size_t)row * K);
#pragma unroll
    for (int i = 0; i < 4; ++i) {
        // exact fp32 division matches reference rounding; rintf = round-half-even
        int b0 = (int)fminf(fmaxf(rintf(v[i].x / s), -QMAX), QMAX);
        int b1 = (int)fminf(fmaxf(rintf(v[i].y / s), -QMAX), QMAX);
        int b2 = (int)fminf(fmaxf(rintf(v[i].z / s), -QMAX), QMAX);
        int b3 = (int)fminf(fmaxf(rintf(v[i].w / s), -QMAX), QMAX);
        qrow[t + 256 * i] =
            (b0 & 0xff) | ((b1 & 0xff) << 8) | ((b2 & 0xff) << 16) | ((b3 & 0xff) << 24);
    }
}

// ---------------- int8 GEMM: 128x256 block, wave tile 64x128 ----------------
// C[t,o] = sum_k qx[t,k]*qw[o,k]. BK=64 bytes, 256 threads = 4 waves (2x2),
// wave tile 64x128 = 4x8 grid of mfma_i32_16x16x64_i8 (32 MFMA / 12 frag
// reads per wave-iter -> LDS bytes per MFMA op halved vs 64x64 wave tile).
// LDS xor-swizzle: chunk (row r, col c) stored at column (c + (r>>1)) & 3,
// implemented by permuting the global source address (global_load_lds pins
// LDS dest = uniform base + lane*16). Readers use (q + (l16>>1)) & 3 —
// invariant under wm/wn/mi/ni offsets (all even multiples of 8 rows).
__global__ __launch_bounds__(256, 2) void gemm_i8_kernel(
    const signed char* __restrict__ qx,   // [M,K]
    const signed char* __restrict__ qw,   // [N,K]
    const float* __restrict__ sx,         // [M]
    const float* __restrict__ sw,         // [N]
    const float* __restrict__ bias,       // [N]
    float* __restrict__ out,              // [M,N]
    int M, int N, int K)
{
    __shared__ signed char smA[128 * 64];   // 8 KB
    __shared__ signed char smB[256 * 64];   // 16 KB

    const int t = threadIdx.x;
    const int lane = t & 63;
    const int wave = t >> 6;
    const int bm = blockIdx.y, bn = blockIdx.x;
    const int wm = (wave >> 1) * 64;   // wave row offset in 128
    const int wn = (wave & 1) * 128;   // wave col offset in 256

    int4v acc[4][8];
#pragma unroll
    for (int i = 0; i < 4; ++i)
#pragma unroll
        for (int j = 0; j < 8; ++j)
            acc[i][j] = (int4v)0;

    // Staging map: chunk ch = t + 256*p -> row ch>>2, swizzled col pos ch&3.
    // Source col c_src = ((t&3) - ((t>>3)&3)) & 3  (p-invariant: 256*p>>3 ≡ 0 mod 4*8).
    const int r0 = t >> 2;
    const int c_src = ((t & 3) - ((t >> 3) & 3) + 4) & 3;
    const signed char* gA0 = qx + (size_t)(bm * 128 + r0) * K + c_src * 16;
    const signed char* gA1 = gA0 + (size_t)64 * K;
    const signed char* gB0 = qw + (size_t)(bn * 256 + r0) * K + c_src * 16;
    const signed char* gB1 = gB0 + (size_t)64 * K;
    const signed char* gB2 = gB1 + (size_t)64 * K;
    const signed char* gB3 = gB2 + (size_t)64 * K;
    signed char* lA0 = smA + wave * 1024;          // wave-uniform LDS bases
    signed char* lA1 = smA + 4096 + wave * 1024;
    signed char* lB0 = smB + wave * 1024;
    signed char* lB1 = smB + 4096 + wave * 1024;
    signed char* lB2 = smB + 8192 + wave * 1024;
    signed char* lB3 = smB + 12288 + wave * 1024;

    // Fragment read offsets (A: row wm+mi*16+l16, k-quad q=lane>>4)
    const int l16 = lane & 15;
    const int q = lane >> 4;
    const int cr = (q + ((l16 >> 1) & 3)) & 3;
    const int offA = (wm + l16) * 64 + cr * 16;
    const int offB = (wn + l16) * 64 + cr * 16;

    const int KITER = K >> 6;
    for (int kk = 0; kk < KITER; ++kk) {
        __builtin_amdgcn_global_load_lds((const void*)gA0, (void*)lA0, 16, 0, 0);
        __builtin_amdgcn_global_load_lds((const void*)gA1, (void*)lA1, 16, 0, 0);
        __builtin_amdgcn_global_load_lds((const void*)gB0, (void*)lB0, 16, 0, 0);
        __builtin_amdgcn_global_load_lds((const void*)gB1, (void*)lB1, 16, 0, 0);
        __builtin_amdgcn_global_load_lds((const void*)gB2, (void*)lB2, 16, 0, 0);
        __builtin_amdgcn_global_load_lds((const void*)gB3, (void*)lB3, 16, 0, 0);
        gA0 += 64; gA1 += 64; gB0 += 64; gB1 += 64; gB2 += 64; gB3 += 64;
        __syncthreads();

        int4v aF[4], bF[8];
#pragma unroll
        for (int mi = 0; mi < 4; ++mi)
            aF[mi] = *(const int4v*)(smA + offA + mi * 1024);
#pragma unroll
        for (int ni = 0; ni < 8; ++ni)
            bF[ni] = *(const int4v*)(smB + offB + ni * 1024);
#pragma unroll
        for (int mi = 0; mi < 4; ++mi)
#pragma unroll
            for (int ni = 0; ni < 8; ++ni)
                acc[mi][ni] = __builtin_amdgcn_mfma_i32_16x16x64_i8(
                    aF[mi], bF[ni], acc[mi][ni], 0, 0, 0);
        __syncthreads();
    }

    // Epilogue: C/D layout col=lane&15, row=(lane>>4)*4+reg
    const int col0 = lane & 15;
    const int row0 = (lane >> 4) * 4;
#pragma unroll
    for (int mi = 0; mi < 4; ++mi) {
#pragma unroll
        for (int r = 0; r < 4; ++r) {
            const int gm = bm * 128 + wm + mi * 16 + row0 + r;
            const float sxr = sx[gm];
            float* orow = out + (size_t)gm * N + bn * 256 + wn;
#pragma unroll
            for (int ni = 0; ni < 8; ++ni) {
                const int gn_local = ni * 16 + col0;
                const int gn = bn * 256 + wn + gn_local;
                orow[gn_local] = (float)acc[mi][ni][r] * (sxr * sw[gn]) + bias[gn];
            }
        }
    }
    (void)M;
}

extern "C" void kernel_launch(void* const* d_in, const int* in_sizes, int n_in,
                              void* d_out, int out_size, void* d_ws, size_t ws_size,
                              hipStream_t stream) {
    const float* x    = (const float*)d_in[0];
    const float* W    = (const float*)d_in[1];
    const float* bias = (const float*)d_in[2];
    float* out = (float*)d_out;

    const int dout = in_sizes[2];               // 4096
    const int din  = in_sizes[1] / dout;        // 4096
    const int T    = in_sizes[0] / din;         // 8192

    signed char* qx = (signed char*)d_ws;
    signed char* qw = qx + (size_t)T * din;
    float* sx = (float*)(qw + (size_t)dout * din);
    float* sw = sx + T;

    quant_rows_kernel<<<T,    256, 0, stream>>>(x, qx, sx, din);
    quant_rows_kernel<<<dout, 256, 0, stream>>>(W, qw, sw, din);

    dim3 grid(dout / 256, T / 128);
    gemm_i8_kernel<<<grid, 256, 0, stream>>>(qx, qw, sx, sw, bias, out, T, dout, din);

    (void)n_in; (void)out_size; (void)ws_size;
}